// Round 13
// baseline (146.446 us; speedup 1.0000x reference)
//
#include <hip/hip_runtime.h>
#include <math.h>

// OnlineTripletLoss on MI355X — Round 13.
// R12: prep-coalescing fix NEUTRAL (total 141.8) -> the ~56 us outside fused is tied to
//      the 16 MB pan workspace (R1 with 64 KB ws had ~8 us overhead over 5 launches),
//      not to prep's store pattern.
// Changes:
//  (1) eliminate pan + prep: fused stages raw fp32 e rows (R2-verified pattern),
//      converts f32->hi/lo f16 in registers, ds_writes into frag layout. ws -> ~80 KB.
//      Pipeline: vmem wait lands at convert after a full compute phase (1-deep, same
//      as DMA version); barrier vmcnt(0) trivially satisfied.
//  (2) squared-domain epilogue: hp/hn_fall/hn_semi kept as d^2 (monotonic), sqrt only
//      in the final N-element reduction. Removes 256 v_sqrt + clamps per thread.
// ws: sq[N] | hp2[N] | hnf2[N] | hns2[N] | bars[1024]

constexpr float MARGIN = 0.3f;

typedef _Float16 half8    __attribute__((ext_vector_type(8)));
typedef float    floatx16 __attribute__((ext_vector_type(16)));

// one wave per row: sq + per-row init + barrier counters
__global__ __launch_bounds__(256)
void sq_init_kernel(const float* __restrict__ e, float* __restrict__ sq,
                    unsigned int* __restrict__ hp2, unsigned int* __restrict__ hnf2,
                    unsigned int* __restrict__ hns2, unsigned int* __restrict__ bars,
                    int N, int D) {
    if (blockIdx.x == 0 && threadIdx.x < 32) bars[threadIdx.x * 32] = 0u;
    const int row  = blockIdx.x * 4 + (threadIdx.x >> 6);
    const int lane = threadIdx.x & 63;
    if (row >= N) return;
    const float* er = e + (size_t)row * D;
    float s = 0.f;
    for (int k0 = lane * 8; k0 < D; k0 += 512) {
        const float4 x0 = *(const float4*)&er[k0];
        const float4 x1 = *(const float4*)&er[k0 + 4];
        s += x0.x*x0.x + x0.y*x0.y + x0.z*x0.z + x0.w*x0.w
           + x1.x*x1.x + x1.y*x1.y + x1.z*x1.z + x1.w*x1.w;
    }
    #pragma unroll
    for (int off = 32; off; off >>= 1) s += __shfl_down(s, off, 64);
    if (lane == 0) {
        sq[row]   = s;
        hp2[row]  = 0u;           // max identity (d2 >= 0)
        hnf2[row] = 0u;
        hns2[row] = 0x7f800000u;  // +inf (min identity)
    }
}

// Fused kernel: tile 256(rows) x 128(cols), 512 thr = 8 waves (4x2) of 64x64.
// In-kernel f32->f16 hi/lo staging, double-buffered LDS, swapped-operand MFMA,
// squared-domain epilogue, per-row-panel barrier, last-block final reduction.
__global__ __launch_bounds__(512, 4)
void fused_kernel(const float* __restrict__ e, const int* __restrict__ labels,
                  const float* __restrict__ sq,
                  unsigned int* __restrict__ hp2,
                  unsigned int* __restrict__ hnf2,
                  unsigned int* __restrict__ hns2,
                  unsigned int* __restrict__ bars,
                  float* __restrict__ out,
                  int N, int D, unsigned int nrowblocks, unsigned int nblocks) {
    // per buffer (12288 halves = 24 KB): A[kcl(4)][r(256)][8] | B[kcl(4)][r(128)][8]
    // kcl: 0,1 = hi chunks of (2kk, 2kk+1); 2,3 = matching lo chunks.
    __shared__ __attribute__((aligned(16))) _Float16 S[2][12288];   // 48 KB
    __shared__ float sq_r[256], sq_c[128], hp_r[256];
    __shared__ int   lab_r[256], lab_c[128];
    __shared__ int   lastflag;

    const int tid  = threadIdx.x;
    const int lane = tid & 63;
    const int wave = tid >> 6;            // 0..7
    const int wr = (wave >> 1) * 64;      // 0,64,128,192
    const int wc = (wave & 1) * 64;       // 0,64
    const int mrow = lane & 31;
    const int half_id = lane >> 5;

    const int j  = blockIdx.x & 7;
    const int i  = blockIdx.x >> 3;       // 0..63
    const int px = (j & 3) * 8 + (i & 7);         // 0..31 (128-col tiles)
    const int py = (j >> 2) * 8 + (i >> 3);       // 0..15 (256-row tiles)
    const int rowBase = py * 256;
    const int colBase = px * 128;

    if (tid < 256) {
        sq_r[tid]  = sq[rowBase + tid];
        lab_r[tid] = labels[rowBase + tid];
    } else if (tid < 384) {
        const int t = tid - 256;
        sq_c[t]  = sq[colBase + t];
        lab_c[t] = labels[colBase + t];
    }

    floatx16 acc[2][2];
    #pragma unroll
    for (int a = 0; a < 2; ++a)
        #pragma unroll
        for (int b = 0; b < 2; ++b)
            #pragma unroll
            for (int r = 0; r < 16; ++r) acc[a][b][r] = 0.f;

    // staging registers: every thread one A chunk (row=tid>>1, ch=tid&1, 8 floats);
    // threads < 256 also one B chunk.
    const int srow = tid >> 1, sch = tid & 1;
    float4 ra0, ra1, rb0, rb1;
    auto loadRegs = [&](int kkv) {
        const float* ga = &e[(size_t)(rowBase + srow) * D + kkv * 16 + sch * 8];
        ra0 = *(const float4*)ga;
        ra1 = *(const float4*)(ga + 4);
        if (tid < 256) {
            const float* gb = &e[(size_t)(colBase + srow) * D + kkv * 16 + sch * 8];
            rb0 = *(const float4*)gb;
            rb1 = *(const float4*)(gb + 4);
        }
    };
    auto cvtWrite = [&](int b) {
        {
            const float xv[8] = {ra0.x, ra0.y, ra0.z, ra0.w, ra1.x, ra1.y, ra1.z, ra1.w};
            half8 hi, lo;
            #pragma unroll
            for (int q = 0; q < 8; ++q) {
                _Float16 h = (_Float16)xv[q];
                hi[q] = h;
                lo[q] = (_Float16)(xv[q] - (float)h);
            }
            *(half8*)&S[b][(sch * 256 + srow) * 8]       = hi;
            *(half8*)&S[b][((2 + sch) * 256 + srow) * 8] = lo;
        }
        if (tid < 256) {
            const float xv[8] = {rb0.x, rb0.y, rb0.z, rb0.w, rb1.x, rb1.y, rb1.z, rb1.w};
            half8 hi, lo;
            #pragma unroll
            for (int q = 0; q < 8; ++q) {
                _Float16 h = (_Float16)xv[q];
                hi[q] = h;
                lo[q] = (_Float16)(xv[q] - (float)h);
            }
            *(half8*)&S[b][8192 + (sch * 128 + srow) * 8]       = hi;
            *(half8*)&S[b][8192 + ((2 + sch) * 128 + srow) * 8] = lo;
        }
    };

    loadRegs(0);

    #pragma unroll 1
    for (int kk = 0; kk < 32; ++kk) {
        const int b = kk & 1;
        cvtWrite(b);                    // waits the loads issued last iteration
        __syncthreads();                // writes visible; vmcnt already drained at use
        if (kk + 1 < 32) loadRegs(kk + 1);
        const int rA = wr + mrow, cB = wc + mrow;
        const half8 ah0 = *(const half8*)&S[b][(half_id * 256 + rA) * 8];
        const half8 ah1 = *(const half8*)&S[b][(half_id * 256 + rA + 32) * 8];
        const half8 al0 = *(const half8*)&S[b][((2 + half_id) * 256 + rA) * 8];
        const half8 al1 = *(const half8*)&S[b][((2 + half_id) * 256 + rA + 32) * 8];
        const half8 bh0 = *(const half8*)&S[b][8192 + (half_id * 128 + cB) * 8];
        const half8 bh1 = *(const half8*)&S[b][8192 + (half_id * 128 + cB + 32) * 8];
        const half8 bl0 = *(const half8*)&S[b][8192 + ((2 + half_id) * 128 + cB) * 8];
        const half8 bl1 = *(const half8*)&S[b][8192 + ((2 + half_id) * 128 + cB + 32) * 8];
        acc[0][0] = __builtin_amdgcn_mfma_f32_32x32x16_f16(bh0, ah0, acc[0][0], 0, 0, 0);
        acc[0][1] = __builtin_amdgcn_mfma_f32_32x32x16_f16(bh0, ah1, acc[0][1], 0, 0, 0);
        acc[1][0] = __builtin_amdgcn_mfma_f32_32x32x16_f16(bh1, ah0, acc[1][0], 0, 0, 0);
        acc[1][1] = __builtin_amdgcn_mfma_f32_32x32x16_f16(bh1, ah1, acc[1][1], 0, 0, 0);
        acc[0][0] = __builtin_amdgcn_mfma_f32_32x32x16_f16(bl0, ah0, acc[0][0], 0, 0, 0);
        acc[0][1] = __builtin_amdgcn_mfma_f32_32x32x16_f16(bl0, ah1, acc[0][1], 0, 0, 0);
        acc[1][0] = __builtin_amdgcn_mfma_f32_32x32x16_f16(bl1, ah0, acc[1][0], 0, 0, 0);
        acc[1][1] = __builtin_amdgcn_mfma_f32_32x32x16_f16(bl1, ah1, acc[1][1], 0, 0, 0);
        acc[0][0] = __builtin_amdgcn_mfma_f32_32x32x16_f16(bh0, al0, acc[0][0], 0, 0, 0);
        acc[0][1] = __builtin_amdgcn_mfma_f32_32x32x16_f16(bh0, al1, acc[0][1], 0, 0, 0);
        acc[1][0] = __builtin_amdgcn_mfma_f32_32x32x16_f16(bh1, al0, acc[1][0], 0, 0, 0);
        acc[1][1] = __builtin_amdgcn_mfma_f32_32x32x16_f16(bh1, al1, acc[1][1], 0, 0, 0);
    }

    // ---- epilogue (squared domain): rows in lanes. row(ai) = wr + ai*32 + mrow ----
    float sqr[2]; int labr[2];
    #pragma unroll
    for (int ai = 0; ai < 2; ++ai) {
        sqr[ai]  = sq_r[wr + ai * 32 + mrow];
        labr[ai] = lab_r[wr + ai * 32 + mrow];
    }

    // ---- phase 1: hp2 / hnf2 row maxima of d^2 ----
    #pragma unroll
    for (int ai = 0; ai < 2; ++ai) {
        float vp = 0.f, vn = 0.f;
        #pragma unroll
        for (int bj = 0; bj < 2; ++bj) {
            #pragma unroll
            for (int r = 0; r < 16; ++r) {
                const int c = wc + bj * 32 + (r & 3) + 8 * (r >> 2) + 4 * half_id;
                const float d2 = fmaxf(sqr[ai] + sq_c[c] - 2.0f * acc[bj][ai][r], 1e-12f);
                const bool pos = (labr[ai] == lab_c[c]);
                vp = fmaxf(vp, pos ? d2 : 0.f);
                vn = fmaxf(vn, pos ? 0.f : d2);
            }
        }
        vp = fmaxf(vp, __shfl_xor(vp, 32, 64));
        vn = fmaxf(vn, __shfl_xor(vn, 32, 64));
        if (half_id == 0) {
            atomicMax(&hp2[rowBase + wr + ai * 32 + mrow],  __float_as_uint(vp));
            atomicMax(&hnf2[rowBase + wr + ai * 32 + mrow], __float_as_uint(vn));
        }
    }

    // ---- per-row-panel barrier: the 32 blocks sharing py ----
    __syncthreads();
    unsigned int* ctr = &bars[py * 32];
    if (tid == 0) {
        __threadfence();
        atomicAdd(ctr, 1u);
        while (__hip_atomic_load(ctr, __ATOMIC_ACQUIRE, __HIP_MEMORY_SCOPE_AGENT)
               < nrowblocks)
            __builtin_amdgcn_s_sleep(32);
    }
    __syncthreads();
    if (tid < 256)
        hp_r[tid] = __uint_as_float(__hip_atomic_load(&hp2[rowBase + tid],
                                    __ATOMIC_RELAXED, __HIP_MEMORY_SCOPE_AGENT));
    __syncthreads();

    // ---- phase 2: hns2 = min{d2 : neg, d2 > hp2} ----
    #pragma unroll
    for (int ai = 0; ai < 2; ++ai) {
        const float hpv2 = hp_r[wr + ai * 32 + mrow];
        float vm = __builtin_inff();
        #pragma unroll
        for (int bj = 0; bj < 2; ++bj) {
            #pragma unroll
            for (int r = 0; r < 16; ++r) {
                const int c = wc + bj * 32 + (r & 3) + 8 * (r >> 2) + 4 * half_id;
                const float d2 = fmaxf(sqr[ai] + sq_c[c] - 2.0f * acc[bj][ai][r], 1e-12f);
                const bool cand = (labr[ai] != lab_c[c]) && (d2 > hpv2);
                vm = fminf(vm, cand ? d2 : __builtin_inff());
            }
        }
        vm = fminf(vm, __shfl_xor(vm, 32, 64));
        if (half_id == 0)
            atomicMin(&hns2[rowBase + wr + ai * 32 + mrow], __float_as_uint(vm));
    }

    // ---- last-block final reduction (sqrt here, N values only) ----
    __syncthreads();
    if (tid == 0) {
        __threadfence();
        unsigned int old = atomicAdd(&bars[992], 1u);
        lastflag = (old == nblocks - 1) ? 1 : 0;
    }
    __syncthreads();
    if (!lastflag) return;
    if (tid == 0) __threadfence();
    __syncthreads();

    float* FS = (float*)&S[0][0];
    int*   IC = (int*)(FS + 512);
    int*   IA = IC + 512;
    int any = 0;
    for (int r = tid; r < N; r += 512) {
        float h  = sqrtf(__uint_as_float(__hip_atomic_load(&hp2[r],  __ATOMIC_RELAXED, __HIP_MEMORY_SCOPE_AGENT)));
        float hs = sqrtf(__uint_as_float(__hip_atomic_load(&hns2[r], __ATOMIC_RELAXED, __HIP_MEMORY_SCOPE_AGENT)));
        any |= (hs < h + MARGIN) ? 1 : 0;
    }
    IA[tid] = any;
    __syncthreads();
    for (int s = 256; s; s >>= 1) {
        if (tid < s) IA[tid] |= IA[tid + s];
        __syncthreads();
    }
    const bool has_semi = IA[0] != 0;
    float sum = 0.f; int valid = 0;
    for (int r = tid; r < N; r += 512) {
        float h  = sqrtf(__uint_as_float(__hip_atomic_load(&hp2[r], __ATOMIC_RELAXED, __HIP_MEMORY_SCOPE_AGENT)));
        float hn = has_semi
            ? sqrtf(__uint_as_float(__hip_atomic_load(&hns2[r], __ATOMIC_RELAXED, __HIP_MEMORY_SCOPE_AGENT)))
            : sqrtf(__uint_as_float(__hip_atomic_load(&hnf2[r], __ATOMIC_RELAXED, __HIP_MEMORY_SCOPE_AGENT)));
        float t = fmaxf(h - hn + MARGIN, 0.f);
        if (!(t > 0.f)) t = 0.f;        // -inf guard (hn=+inf rows)
        sum += t;
        valid += (t > 0.f) ? 1 : 0;
    }
    FS[tid] = sum; IC[tid] = valid;
    __syncthreads();
    for (int s = 256; s; s >>= 1) {
        if (tid < s) { FS[tid] += FS[tid + s]; IC[tid] += IC[tid + s]; }
        __syncthreads();
    }
    if (tid == 0) {
        float total = FS[0]; int v = IC[0];
        out[0] = (v > 0) ? (total / (float)v) : (total / (float)N);
    }
}

extern "C" void kernel_launch(void* const* d_in, const int* in_sizes, int n_in,
                              void* d_out, int out_size, void* d_ws, size_t ws_size,
                              hipStream_t stream) {
    const float* e      = (const float*)d_in[0];
    const int*   labels = (const int*)d_in[1];
    const int N = in_sizes[1];
    const int D = in_sizes[0] / N;
    float* out = (float*)d_out;

    float*        sq   = (float*)d_ws;
    unsigned int* hp2  = (unsigned int*)d_ws + N;
    unsigned int* hnf2 = hp2 + N;
    unsigned int* hns2 = hnf2 + N;
    unsigned int* bars = hns2 + N;     // 32 counters (128B-spaced) + done @992

    sq_init_kernel<<<N / 4, 256, 0, stream>>>(e, sq, hp2, hnf2, hns2, bars, N, D);

    const int ntx = N / 128, nty = N / 256;  // 32 x 16 tiles = 512 blocks = 2/CU
    fused_kernel<<<ntx * nty, 512, 0, stream>>>(e, labels, sq, hp2, hnf2, hns2,
                                                bars, out, N, D,
                                                (unsigned)ntx, (unsigned)(ntx * nty));
}